// Round 12
// baseline (309.918 us; speedup 1.0000x reference)
//
#include <hip/hip_runtime.h>

// BSPLoss: out = sig1(f1)^2 + 0.5*(sig1(f2)^2 + sig1(f3)^2), f: 8192x1024 fp32.
// sig1^2 = top eig of G = f'f. bf16 MFMA for G and 5 trace-normalized squarings
// (eigenvector only); final lambda = (w' G32 w)/|w|^2 with fp32-accumulated Gram.
// R12: syrk split-K 8 WITH XCD-combo swizzle (b = ky + 8*(t+36m) => XCD=ky,
// per-XCD 2MB m-phases; R10's sk8 regression was the unswizzled 179MB thrash).
// NS 6->5 (absmax pinned at bf16 ULP=128 across NS=8,6; slack bound ~43).

#define DIM 1024
#define NROW 8192
#define MSZ (DIM*DIM)
#define NS 5

typedef __attribute__((ext_vector_type(8))) short short8;
typedef __attribute__((ext_vector_type(4))) float f32x4;

__device__ inline float bf2f(unsigned short u) {
    union { unsigned i; float f; } x; x.i = ((unsigned)u) << 16; return x.f;
}
__device__ inline unsigned short f2bf(float f) {
    union { float f; unsigned i; } x; x.f = f;
    unsigned r = x.i + 0x7FFFu + ((x.i >> 16) & 1u);
    return (unsigned short)(r >> 16);
}
__device__ inline void gload16(const void* g, void* l) {
    __builtin_amdgcn_global_load_lds(
        (const __attribute__((address_space(1))) unsigned int*)g,
        (__attribute__((address_space(3))) unsigned int*)l, 16, 0, 0);
}

// f fp32 [NROW][DIM] -> ft bf16 [DIM][NROW] (transposed), per matrix m.
__global__ __launch_bounds__(256)
void tconv_k(const float* __restrict__ f0, const float* __restrict__ f1,
             const float* __restrict__ f2, unsigned short* __restrict__ ft) {
    const int m = blockIdx.z;
    const float* f = (m == 0) ? f0 : (m == 1 ? f1 : f2);
    unsigned short* o = ft + (size_t)m * DIM * NROW;
    __shared__ float T[64][68];
    const int c0 = blockIdx.x * 64, r0 = blockIdx.y * 64;
    const int tid = threadIdx.x;
    const int cx = (tid & 15) * 4, ry = tid >> 4;
#pragma unroll
    for (int i = 0; i < 4; ++i) {
        int r = ry + i * 16;
        float4 v = *(const float4*)&f[(size_t)(r0 + r) * DIM + c0 + cx];
        T[cx + 0][r] = v.x;
        T[cx + 1][r] = v.y;
        T[cx + 2][r] = v.z;
        T[cx + 3][r] = v.w;
    }
    __syncthreads();
#pragma unroll
    for (int i = 0; i < 4; ++i) {
        int c = ry + i * 16;
        float4 g = *(const float4*)&T[c][cx];
        ushort4 u;
        u.x = f2bf(g.x); u.y = f2bf(g.y); u.z = f2bf(g.z); u.w = f2bf(g.w);
        *(ushort4*)&o[(size_t)(c0 + c) * NROW + r0 + cx] = u;
    }
}

// Split-K(8) symmetric SYRK, upper 128-tiles, fp32 atomicAdd into packed G.
// Flat grid 864: b = ky + 8*(tile + 36*m). XCD = b%8 = ky: each XCD streams
// sequential (m, 1024-col K-chunk) phases of 2 MB each (fits per-XCD L2).
// BK=64 as two 32-halves via global_load_lds.
__global__ __launch_bounds__(256)
void syrk_sk(const unsigned short* __restrict__ src, float* __restrict__ Gp) {
    const int b = blockIdx.x;
    const int ky = b & 7;
    const int q = b >> 3;            // 0..107
    const int m = q / 36;
    const int tile = q - m * 36;
    int idx = tile, ti = 0;
    while (idx >= 8 - ti) { idx -= 8 - ti; ++ti; }
    const int tj = ti + idx;
    const int i0 = ti * 128, j0 = tj * 128;
    const unsigned short* S = src + (size_t)m * DIM * NROW;
    float* G = Gp + ((size_t)m * 36 + tile) * 16384;
    const int k0b = ky << 10;        // Kc = 1024

    __shared__ unsigned short As[2 * 128 * 32];
    __shared__ unsigned short Bs[2 * 128 * 32];

    const int tid = threadIdx.x, w = tid >> 6, lane = tid & 63;
    const int wi = w >> 1, wj = w & 1;

    f32x4 acc[4][4];
#pragma unroll
    for (int a = 0; a < 4; ++a)
#pragma unroll
        for (int c = 0; c < 4; ++c) acc[a][c] = (f32x4){0.f, 0.f, 0.f, 0.f};

    const int lr = lane >> 2;
    const int ksw = (((lane & 3) ^ ((lane >> 4) & 3)) * 8);
    const int fr = lane & 15;
    const int slot = (((lane >> 4) ^ ((fr >> 2) & 3)) * 8);

    for (int k0 = k0b; k0 < k0b + 1024; k0 += 64) {
#pragma unroll
        for (int h = 0; h < 2; ++h)
#pragma unroll
            for (int p = 0; p < 2; ++p) {
                int rr = w * 32 + p * 16;
                gload16(S + (size_t)(i0 + rr + lr) * NROW + k0 + h * 32 + ksw,
                        &As[h * 4096 + rr * 32]);
                gload16(S + (size_t)(j0 + rr + lr) * NROW + k0 + h * 32 + ksw,
                        &Bs[h * 4096 + rr * 32]);
            }
        __syncthreads();
#pragma unroll
        for (int h = 0; h < 2; ++h) {
            short8 af[4], bfv[4];
#pragma unroll
            for (int a = 0; a < 4; ++a)
                af[a] = *(const short8*)&As[h * 4096 + (wi * 64 + a * 16 + fr) * 32 + slot];
#pragma unroll
            for (int c = 0; c < 4; ++c)
                bfv[c] = *(const short8*)&Bs[h * 4096 + (wj * 64 + c * 16 + fr) * 32 + slot];
#pragma unroll
            for (int a = 0; a < 4; ++a)
#pragma unroll
                for (int c = 0; c < 4; ++c)
                    acc[a][c] = __builtin_amdgcn_mfma_f32_16x16x32_bf16(
                        af[a], bfv[c], acc[a][c], 0, 0, 0);
        }
        __syncthreads();
    }

    const int qr = (lane >> 4) * 4, cn = lane & 15;
#pragma unroll
    for (int a = 0; a < 4; ++a)
#pragma unroll
        for (int c = 0; c < 4; ++c) {
            int cl = wj * 64 + c * 16 + cn;
#pragma unroll
            for (int reg = 0; reg < 4; ++reg) {
                int rl = wi * 64 + a * 16 + qr + reg;
                atomicAdd(&G[rl * 128 + cl], acc[a][c][reg]);
            }
        }
}

// Packed-upper fp32 G -> full bf16 matrix (mirror via swizzled LDS transpose),
// fused trace -> trout[m]. grid (36,1,3). G32 read-only (kept for ray_k).
__global__ __launch_bounds__(256)
void convert_k(const float* __restrict__ Gp, float* __restrict__ trout,
               unsigned short* __restrict__ dst) {
    const int m = blockIdx.z;
    int idx = blockIdx.x, ti = 0;
    while (idx >= 8 - ti) { idx -= 8 - ti; ++ti; }
    const int tj = ti + idx;
    const int i0 = ti * 128, j0 = tj * 128;
    const float* G = Gp + ((size_t)m * 36 + blockIdx.x) * 16384;
    unsigned short* D = dst + (size_t)m * MSZ;
    __shared__ unsigned short T[128][136];
    const int tid = threadIdx.x;
    const int cx = (tid & 31) * 4, ry = tid >> 5;
    float dtr = 0.f;
#pragma unroll 4
    for (int t = 0; t < 16; ++t) {
        int r = ry + t * 8;
        float4 g = *(const float4*)&G[r * 128 + cx];
        ushort4 o;
        o.x = f2bf(g.x); o.y = f2bf(g.y); o.z = f2bf(g.z); o.w = f2bf(g.w);
        *(ushort4*)&D[(size_t)(i0 + r) * DIM + j0 + cx] = o;
        int rs = r ^ (cx & 124);
        T[cx + 0][rs] = o.x; T[cx + 1][rs] = o.y;
        T[cx + 2][rs] = o.z; T[cx + 3][rs] = o.w;
        if (ti == tj) {
            int d = r - cx;
            if (d >= 0 && d < 4)
                dtr += (d == 0 ? g.x : d == 1 ? g.y : d == 2 ? g.z : g.w);
        }
    }
    if (ti == tj) atomicAdd(&trout[m], dtr);
    if (ti != tj) {
        __syncthreads();
#pragma unroll 4
        for (int t = 0; t < 16; ++t) {
            int p = ry + t * 8;
            int qs = cx ^ (p & 124);
            ushort4 o = *(const ushort4*)&T[p][qs];
            *(ushort4*)&D[(size_t)(j0 + p) * DIM + i0 + cx] = o;
        }
    }
}

// One trace-normalized squaring: dst = (src/tr)^2, symmetric 64-tiles, fused
// scale + mirror + trace. grid (136,1,3). BK=64, two 32-halves (R6-proven).
__global__ __launch_bounds__(256)
void sq_k(const unsigned short* __restrict__ src, const float* __restrict__ trin,
          float* __restrict__ trout, unsigned short* __restrict__ dst) {
    const int m = blockIdx.z;
    const unsigned short* S = src + (size_t)m * MSZ;
    unsigned short* D = dst + (size_t)m * MSZ;
    int idx = blockIdx.x, ti = 0;
    while (idx >= 16 - ti) { idx -= 16 - ti; ++ti; }
    const int tj = ti + idx;
    const int i0 = ti * 64, j0 = tj * 64;
    float tv = trin[m];
    const float sc = 1.f / (tv * tv);

    __shared__ unsigned short As[2 * 64 * 32];
    __shared__ unsigned short Bs[2 * 64 * 32];
    __shared__ unsigned short Ts[64][68];

    const int tid = threadIdx.x, w = tid >> 6, lane = tid & 63;
    const int wi = w >> 1, wj = w & 1;
    f32x4 acc[2][2];
#pragma unroll
    for (int a = 0; a < 2; ++a)
#pragma unroll
        for (int b = 0; b < 2; ++b) acc[a][b] = (f32x4){0.f, 0.f, 0.f, 0.f};

    const int lr = lane >> 2;
    const int ksw = (((lane & 3) ^ ((lane >> 4) & 3)) * 8);
    const int fr = lane & 15;
    const int slot = (((lane >> 4) ^ ((fr >> 2) & 3)) * 8);

    for (int k0 = 0; k0 < DIM; k0 += 64) {
#pragma unroll
        for (int h = 0; h < 2; ++h) {
            gload16(S + (size_t)(i0 + w * 16 + lr) * DIM + k0 + h * 32 + ksw,
                    &As[h * 2048 + w * 16 * 32]);
            gload16(S + (size_t)(j0 + w * 16 + lr) * DIM + k0 + h * 32 + ksw,
                    &Bs[h * 2048 + w * 16 * 32]);
        }
        __syncthreads();
#pragma unroll
        for (int h = 0; h < 2; ++h) {
            short8 af[2], bfv[2];
#pragma unroll
            for (int a = 0; a < 2; ++a)
                af[a] = *(const short8*)&As[h * 2048 + (wi * 32 + a * 16 + fr) * 32 + slot];
#pragma unroll
            for (int c = 0; c < 2; ++c)
                bfv[c] = *(const short8*)&Bs[h * 2048 + (wj * 32 + c * 16 + fr) * 32 + slot];
#pragma unroll
            for (int a = 0; a < 2; ++a)
#pragma unroll
                for (int c = 0; c < 2; ++c)
                    acc[a][c] = __builtin_amdgcn_mfma_f32_16x16x32_bf16(
                        af[a], bfv[c], acc[a][c], 0, 0, 0);
        }
        __syncthreads();
    }

    const int qr = (lane >> 4) * 4, cn = lane & 15;
#pragma unroll
    for (int a = 0; a < 2; ++a)
#pragma unroll
        for (int b = 0; b < 2; ++b) {
            int cl = wj * 32 + b * 16 + cn;
#pragma unroll
            for (int reg = 0; reg < 4; ++reg) {
                int rl = wi * 32 + a * 16 + qr + reg;
                unsigned short val = f2bf(acc[a][b][reg] * sc);
                D[(size_t)(i0 + rl) * DIM + j0 + cl] = val;
                Ts[cl][rl] = val;
            }
        }
    if (ti == tj && wi == wj) {
        int d = cn - qr;
        if (d >= 0 && d < 4)
            atomicAdd(&trout[m], (acc[0][0][d] + acc[1][1][d]) * sc);
    }
    if (ti != tj) {
        __syncthreads();
        const int cx = (tid & 15) * 4, ry = tid >> 4;
#pragma unroll
        for (int tq = 0; tq < 4; ++tq) {
            int p = ry + tq * 16;
            ushort4 o;
            o.x = Ts[p][cx + 0]; o.y = Ts[p][cx + 1];
            o.z = Ts[p][cx + 2]; o.w = Ts[p][cx + 3];
            *(ushort4*)&D[(size_t)(j0 + p) * DIM + i0 + cx] = o;
        }
    }
}

// vout[row] = sum_j M[row][j] * (vin ? vin[j] : 1), M bf16 symmetric.
__global__ __launch_bounds__(256)
void mv_bf16(const unsigned short* __restrict__ M, const float* __restrict__ vin,
             float* __restrict__ vout) {
    int m = blockIdx.y;
    const unsigned short* A = M + (size_t)m * MSZ;
    int wv = threadIdx.x >> 6, lane = threadIdx.x & 63;
    int row = blockIdx.x * 4 + wv;
    const unsigned short* a = A + (size_t)row * DIM;
    float s = 0.f;
    if (vin) {
        const float* v = vin + m * DIM;
        for (int j = lane; j < DIM; j += 64) s += bf2f(a[j]) * v[j];
    } else {
        for (int j = lane; j < DIM; j += 64) s += bf2f(a[j]);
    }
    for (int off = 32; off; off >>= 1) s += __shfl_down(s, off);
    if (lane == 0) vout[m * DIM + row] = s;
}

// num[m] += w_i' T w_j (x2 off-diag) over packed-upper fp32 tiles. grid (36,3).
__global__ __launch_bounds__(256)
void ray_k(const float* __restrict__ Gp, const float* __restrict__ wv,
           float* __restrict__ num) {
    const int m = blockIdx.y;
    int idx = blockIdx.x, ti = 0;
    while (idx >= 8 - ti) { idx -= 8 - ti; ++ti; }
    const int tj = ti + idx;
    const float* G = Gp + ((size_t)m * 36 + blockIdx.x) * 16384;
    const float* wi = wv + m * DIM + ti * 128;
    const float* wj = wv + m * DIM + tj * 128;
    const int tid = threadIdx.x;
    const int r = tid >> 1, c0 = (tid & 1) * 64;
    float inner = 0.f;
    const float4* g4 = (const float4*)&G[r * 128 + c0];
    const float4* w4 = (const float4*)&wj[c0];
#pragma unroll
    for (int t = 0; t < 16; ++t) {
        float4 g = g4[t], ww = w4[t];
        inner += g.x * ww.x + g.y * ww.y + g.z * ww.z + g.w * ww.w;
    }
    float s = wi[r] * inner;
    for (int off = 32; off; off >>= 1) s += __shfl_down(s, off);
    __shared__ float part[4];
    int lane = tid & 63, wx = tid >> 6;
    if (lane == 0) part[wx] = s;
    __syncthreads();
    if (tid == 0) {
        float tot = part[0] + part[1] + part[2] + part[3];
        if (ti != tj) tot *= 2.f;
        atomicAdd(&num[m], tot);
    }
}

// out = num0/|w0|^2 + 0.5*(num1/|w1|^2 + num2/|w2|^2)
__global__ __launch_bounds__(256)
void final_k(const float* __restrict__ num, const float* __restrict__ w,
             float* __restrict__ out) {
    __shared__ float red[256];
    int tid = threadIdx.x;
    float lam[3];
    for (int m = 0; m < 3; ++m) {
        float s = 0.f;
        for (int i = tid; i < DIM; i += 256) { float x = w[m * DIM + i]; s += x * x; }
        red[tid] = s; __syncthreads();
        for (int off = 128; off; off >>= 1) {
            if (tid < off) red[tid] += red[tid + off];
            __syncthreads();
        }
        lam[m] = num[m] / red[0]; __syncthreads();
    }
    if (tid == 0) out[0] = lam[0] + 0.5f * (lam[1] + lam[2]);
}

extern "C" void kernel_launch(void* const* d_in, const int* in_sizes, int n_in,
                              void* d_out, int out_size, void* d_ws, size_t ws_size,
                              hipStream_t stream) {
    const float* f0 = (const float*)d_in[0];
    const float* f1 = (const float*)d_in[1];
    const float* f2 = (const float*)d_in[2];

    char* base = (char*)d_ws;
    unsigned short* ft = (unsigned short*)base;                   // 48 MB bf16 f^T x3
    unsigned short* Q  = (unsigned short*)base;                   // overlays ft (dead after syrk)
    unsigned short* P  = (unsigned short*)(base + 50331648);      // 6 MB bf16 M x3
    float* G32 = (float*)(base + 56623104);                       // 7.08 MB packed-upper fp32 (LIVE)
    float* trbuf = (float*)(base + 63700992);                     // 64 floats (zeroed)
    float* num = trbuf + 40;                                      // 3 floats (zeroed region)
    float* v = (float*)(base + 63701248);                         // 3*1024
    float* w = v + 3 * DIM;                                       // 3*1024

    // zero G32 (7077888 B) + trbuf/num (256 B) in one async memset
    hipMemsetAsync(G32, 0, 7078144, stream);

    dim3 gt(DIM / 64, NROW / 64, 3);
    tconv_k<<<gt, 256, 0, stream>>>(f0, f1, f2, ft);

    // G = ft ft' (K=8192), split-K x8, XCD-combo swizzled flat grid (864)
    syrk_sk<<<864, 256, 0, stream>>>(ft, G32);
    // packed fp32 -> full bf16 P + trace (G32 preserved)
    convert_k<<<dim3(36, 1, 3), 256, 0, stream>>>(G32, trbuf, P);

    unsigned short* cur = P;
    unsigned short* nxt = Q;   // Q lives in the dead ft region
    for (int s = 0; s < NS; ++s) {
        sq_k<<<dim3(136, 1, 3), 256, 0, stream>>>(cur, trbuf + s * 3,
                                                  trbuf + (s + 1) * 3, nxt);
        unsigned short* t2 = cur; cur = nxt; nxt = t2;
    }
    // NS=5 (odd) => cur == Q

    dim3 b(256, 1, 1);
    dim3 gm(DIM / 4, 3, 1);
    mv_bf16<<<gm, b, 0, stream>>>(cur, nullptr, v);   // v = M*1
    mv_bf16<<<gm, b, 0, stream>>>(cur, v, w);         // w = M*v (polish)

    // num[m] = w' G32 w  (fp32 Gram, packed upper)
    ray_k<<<dim3(36, 3, 1), 256, 0, stream>>>(G32, w, num);
    final_k<<<1, 256, 0, stream>>>(num, w, (float*)d_out);
}

// Round 13
// 289.788 us; speedup vs baseline: 1.0695x; 1.0695x over previous
//
#include <hip/hip_runtime.h>

// BSPLoss: out = sig1(f1)^2 + 0.5*(sig1(f2)^2 + sig1(f3)^2), f: 8192x1024 fp32.
// sig1^2 = top eig of G = f'f. bf16 MFMA for G and 5 trace-normalized squarings
// (eigenvector only); final lambda = (w' G32 w)/|w|^2 with fp32-accumulated Gram.
// R13: recombine proven-best knobs. syrk = R11's sk4 + XCD-combo swizzle
// (62 us; R12 proved sk8 loses ~19 us to atomic contention independent of
// fetch/occupancy). NS=5 kept from R12 (absmax 256 < 596).

#define DIM 1024
#define NROW 8192
#define MSZ (DIM*DIM)
#define NS 5

typedef __attribute__((ext_vector_type(8))) short short8;
typedef __attribute__((ext_vector_type(4))) float f32x4;

__device__ inline float bf2f(unsigned short u) {
    union { unsigned i; float f; } x; x.i = ((unsigned)u) << 16; return x.f;
}
__device__ inline unsigned short f2bf(float f) {
    union { float f; unsigned i; } x; x.f = f;
    unsigned r = x.i + 0x7FFFu + ((x.i >> 16) & 1u);
    return (unsigned short)(r >> 16);
}
__device__ inline void gload16(const void* g, void* l) {
    __builtin_amdgcn_global_load_lds(
        (const __attribute__((address_space(1))) unsigned int*)g,
        (__attribute__((address_space(3))) unsigned int*)l, 16, 0, 0);
}

// f fp32 [NROW][DIM] -> ft bf16 [DIM][NROW] (transposed), per matrix m.
__global__ __launch_bounds__(256)
void tconv_k(const float* __restrict__ f0, const float* __restrict__ f1,
             const float* __restrict__ f2, unsigned short* __restrict__ ft) {
    const int m = blockIdx.z;
    const float* f = (m == 0) ? f0 : (m == 1 ? f1 : f2);
    unsigned short* o = ft + (size_t)m * DIM * NROW;
    __shared__ float T[64][68];
    const int c0 = blockIdx.x * 64, r0 = blockIdx.y * 64;
    const int tid = threadIdx.x;
    const int cx = (tid & 15) * 4, ry = tid >> 4;
#pragma unroll
    for (int i = 0; i < 4; ++i) {
        int r = ry + i * 16;
        float4 v = *(const float4*)&f[(size_t)(r0 + r) * DIM + c0 + cx];
        T[cx + 0][r] = v.x;
        T[cx + 1][r] = v.y;
        T[cx + 2][r] = v.z;
        T[cx + 3][r] = v.w;
    }
    __syncthreads();
#pragma unroll
    for (int i = 0; i < 4; ++i) {
        int c = ry + i * 16;
        float4 g = *(const float4*)&T[c][cx];
        ushort4 u;
        u.x = f2bf(g.x); u.y = f2bf(g.y); u.z = f2bf(g.z); u.w = f2bf(g.w);
        *(ushort4*)&o[(size_t)(c0 + c) * NROW + r0 + cx] = u;
    }
}

// Split-K(4) symmetric SYRK, upper 128-tiles, fp32 atomicAdd into packed G.
// Flat grid 432: b = ky + 4*(tile + 36*m). XCD = b%8 = ky + 4*(tile&1):
// each XCD streams one (m, 2048-col K-chunk) = 4 MB, fitting its L2.
// BK=64 as two 32-halves via global_load_lds (R11-proven: 62 us, FETCH~50MB).
__global__ __launch_bounds__(256)
void syrk_sk(const unsigned short* __restrict__ src, float* __restrict__ Gp) {
    const int b = blockIdx.x;
    const int ky = b & 3;
    const int q = b >> 2;            // 0..107
    const int m = q / 36;
    const int tile = q - m * 36;
    int idx = tile, ti = 0;
    while (idx >= 8 - ti) { idx -= 8 - ti; ++ti; }
    const int tj = ti + idx;
    const int i0 = ti * 128, j0 = tj * 128;
    const unsigned short* S = src + (size_t)m * DIM * NROW;
    float* G = Gp + ((size_t)m * 36 + tile) * 16384;
    const int k0b = ky << 11;        // Kc = 2048

    __shared__ unsigned short As[2 * 128 * 32];
    __shared__ unsigned short Bs[2 * 128 * 32];

    const int tid = threadIdx.x, w = tid >> 6, lane = tid & 63;
    const int wi = w >> 1, wj = w & 1;

    f32x4 acc[4][4];
#pragma unroll
    for (int a = 0; a < 4; ++a)
#pragma unroll
        for (int c = 0; c < 4; ++c) acc[a][c] = (f32x4){0.f, 0.f, 0.f, 0.f};

    const int lr = lane >> 2;
    const int ksw = (((lane & 3) ^ ((lane >> 4) & 3)) * 8);
    const int fr = lane & 15;
    const int slot = (((lane >> 4) ^ ((fr >> 2) & 3)) * 8);

    for (int k0 = k0b; k0 < k0b + 2048; k0 += 64) {
#pragma unroll
        for (int h = 0; h < 2; ++h)
#pragma unroll
            for (int p = 0; p < 2; ++p) {
                int rr = w * 32 + p * 16;
                gload16(S + (size_t)(i0 + rr + lr) * NROW + k0 + h * 32 + ksw,
                        &As[h * 4096 + rr * 32]);
                gload16(S + (size_t)(j0 + rr + lr) * NROW + k0 + h * 32 + ksw,
                        &Bs[h * 4096 + rr * 32]);
            }
        __syncthreads();
#pragma unroll
        for (int h = 0; h < 2; ++h) {
            short8 af[4], bfv[4];
#pragma unroll
            for (int a = 0; a < 4; ++a)
                af[a] = *(const short8*)&As[h * 4096 + (wi * 64 + a * 16 + fr) * 32 + slot];
#pragma unroll
            for (int c = 0; c < 4; ++c)
                bfv[c] = *(const short8*)&Bs[h * 4096 + (wj * 64 + c * 16 + fr) * 32 + slot];
#pragma unroll
            for (int a = 0; a < 4; ++a)
#pragma unroll
                for (int c = 0; c < 4; ++c)
                    acc[a][c] = __builtin_amdgcn_mfma_f32_16x16x32_bf16(
                        af[a], bfv[c], acc[a][c], 0, 0, 0);
        }
        __syncthreads();
    }

    const int qr = (lane >> 4) * 4, cn = lane & 15;
#pragma unroll
    for (int a = 0; a < 4; ++a)
#pragma unroll
        for (int c = 0; c < 4; ++c) {
            int cl = wj * 64 + c * 16 + cn;
#pragma unroll
            for (int reg = 0; reg < 4; ++reg) {
                int rl = wi * 64 + a * 16 + qr + reg;
                atomicAdd(&G[rl * 128 + cl], acc[a][c][reg]);
            }
        }
}

// Packed-upper fp32 G -> full bf16 matrix (mirror via swizzled LDS transpose),
// fused trace -> trout[m]. grid (36,1,3). G32 read-only (kept for ray_k).
__global__ __launch_bounds__(256)
void convert_k(const float* __restrict__ Gp, float* __restrict__ trout,
               unsigned short* __restrict__ dst) {
    const int m = blockIdx.z;
    int idx = blockIdx.x, ti = 0;
    while (idx >= 8 - ti) { idx -= 8 - ti; ++ti; }
    const int tj = ti + idx;
    const int i0 = ti * 128, j0 = tj * 128;
    const float* G = Gp + ((size_t)m * 36 + blockIdx.x) * 16384;
    unsigned short* D = dst + (size_t)m * MSZ;
    __shared__ unsigned short T[128][136];
    const int tid = threadIdx.x;
    const int cx = (tid & 31) * 4, ry = tid >> 5;
    float dtr = 0.f;
#pragma unroll 4
    for (int t = 0; t < 16; ++t) {
        int r = ry + t * 8;
        float4 g = *(const float4*)&G[r * 128 + cx];
        ushort4 o;
        o.x = f2bf(g.x); o.y = f2bf(g.y); o.z = f2bf(g.z); o.w = f2bf(g.w);
        *(ushort4*)&D[(size_t)(i0 + r) * DIM + j0 + cx] = o;
        int rs = r ^ (cx & 124);
        T[cx + 0][rs] = o.x; T[cx + 1][rs] = o.y;
        T[cx + 2][rs] = o.z; T[cx + 3][rs] = o.w;
        if (ti == tj) {
            int d = r - cx;
            if (d >= 0 && d < 4)
                dtr += (d == 0 ? g.x : d == 1 ? g.y : d == 2 ? g.z : g.w);
        }
    }
    if (ti == tj) atomicAdd(&trout[m], dtr);
    if (ti != tj) {
        __syncthreads();
#pragma unroll 4
        for (int t = 0; t < 16; ++t) {
            int p = ry + t * 8;
            int qs = cx ^ (p & 124);
            ushort4 o = *(const ushort4*)&T[p][qs];
            *(ushort4*)&D[(size_t)(j0 + p) * DIM + i0 + cx] = o;
        }
    }
}

// One trace-normalized squaring: dst = (src/tr)^2, symmetric 64-tiles, fused
// scale + mirror + trace. grid (136,1,3). BK=64, two 32-halves (R6-proven).
__global__ __launch_bounds__(256)
void sq_k(const unsigned short* __restrict__ src, const float* __restrict__ trin,
          float* __restrict__ trout, unsigned short* __restrict__ dst) {
    const int m = blockIdx.z;
    const unsigned short* S = src + (size_t)m * MSZ;
    unsigned short* D = dst + (size_t)m * MSZ;
    int idx = blockIdx.x, ti = 0;
    while (idx >= 16 - ti) { idx -= 16 - ti; ++ti; }
    const int tj = ti + idx;
    const int i0 = ti * 64, j0 = tj * 64;
    float tv = trin[m];
    const float sc = 1.f / (tv * tv);

    __shared__ unsigned short As[2 * 64 * 32];
    __shared__ unsigned short Bs[2 * 64 * 32];
    __shared__ unsigned short Ts[64][68];

    const int tid = threadIdx.x, w = tid >> 6, lane = tid & 63;
    const int wi = w >> 1, wj = w & 1;
    f32x4 acc[2][2];
#pragma unroll
    for (int a = 0; a < 2; ++a)
#pragma unroll
        for (int b = 0; b < 2; ++b) acc[a][b] = (f32x4){0.f, 0.f, 0.f, 0.f};

    const int lr = lane >> 2;
    const int ksw = (((lane & 3) ^ ((lane >> 4) & 3)) * 8);
    const int fr = lane & 15;
    const int slot = (((lane >> 4) ^ ((fr >> 2) & 3)) * 8);

    for (int k0 = 0; k0 < DIM; k0 += 64) {
#pragma unroll
        for (int h = 0; h < 2; ++h) {
            gload16(S + (size_t)(i0 + w * 16 + lr) * DIM + k0 + h * 32 + ksw,
                    &As[h * 2048 + w * 16 * 32]);
            gload16(S + (size_t)(j0 + w * 16 + lr) * DIM + k0 + h * 32 + ksw,
                    &Bs[h * 2048 + w * 16 * 32]);
        }
        __syncthreads();
#pragma unroll
        for (int h = 0; h < 2; ++h) {
            short8 af[2], bfv[2];
#pragma unroll
            for (int a = 0; a < 2; ++a)
                af[a] = *(const short8*)&As[h * 2048 + (wi * 32 + a * 16 + fr) * 32 + slot];
#pragma unroll
            for (int c = 0; c < 2; ++c)
                bfv[c] = *(const short8*)&Bs[h * 2048 + (wj * 32 + c * 16 + fr) * 32 + slot];
#pragma unroll
            for (int a = 0; a < 2; ++a)
#pragma unroll
                for (int c = 0; c < 2; ++c)
                    acc[a][c] = __builtin_amdgcn_mfma_f32_16x16x32_bf16(
                        af[a], bfv[c], acc[a][c], 0, 0, 0);
        }
        __syncthreads();
    }

    const int qr = (lane >> 4) * 4, cn = lane & 15;
#pragma unroll
    for (int a = 0; a < 2; ++a)
#pragma unroll
        for (int b = 0; b < 2; ++b) {
            int cl = wj * 32 + b * 16 + cn;
#pragma unroll
            for (int reg = 0; reg < 4; ++reg) {
                int rl = wi * 32 + a * 16 + qr + reg;
                unsigned short val = f2bf(acc[a][b][reg] * sc);
                D[(size_t)(i0 + rl) * DIM + j0 + cl] = val;
                Ts[cl][rl] = val;
            }
        }
    if (ti == tj && wi == wj) {
        int d = cn - qr;
        if (d >= 0 && d < 4)
            atomicAdd(&trout[m], (acc[0][0][d] + acc[1][1][d]) * sc);
    }
    if (ti != tj) {
        __syncthreads();
        const int cx = (tid & 15) * 4, ry = tid >> 4;
#pragma unroll
        for (int tq = 0; tq < 4; ++tq) {
            int p = ry + tq * 16;
            ushort4 o;
            o.x = Ts[p][cx + 0]; o.y = Ts[p][cx + 1];
            o.z = Ts[p][cx + 2]; o.w = Ts[p][cx + 3];
            *(ushort4*)&D[(size_t)(j0 + p) * DIM + i0 + cx] = o;
        }
    }
}

// vout[row] = sum_j M[row][j] * (vin ? vin[j] : 1), M bf16 symmetric.
__global__ __launch_bounds__(256)
void mv_bf16(const unsigned short* __restrict__ M, const float* __restrict__ vin,
             float* __restrict__ vout) {
    int m = blockIdx.y;
    const unsigned short* A = M + (size_t)m * MSZ;
    int wv = threadIdx.x >> 6, lane = threadIdx.x & 63;
    int row = blockIdx.x * 4 + wv;
    const unsigned short* a = A + (size_t)row * DIM;
    float s = 0.f;
    if (vin) {
        const float* v = vin + m * DIM;
        for (int j = lane; j < DIM; j += 64) s += bf2f(a[j]) * v[j];
    } else {
        for (int j = lane; j < DIM; j += 64) s += bf2f(a[j]);
    }
    for (int off = 32; off; off >>= 1) s += __shfl_down(s, off);
    if (lane == 0) vout[m * DIM + row] = s;
}

// num[m] += w_i' T w_j (x2 off-diag) over packed-upper fp32 tiles. grid (36,3).
__global__ __launch_bounds__(256)
void ray_k(const float* __restrict__ Gp, const float* __restrict__ wv,
           float* __restrict__ num) {
    const int m = blockIdx.y;
    int idx = blockIdx.x, ti = 0;
    while (idx >= 8 - ti) { idx -= 8 - ti; ++ti; }
    const int tj = ti + idx;
    const float* G = Gp + ((size_t)m * 36 + blockIdx.x) * 16384;
    const float* wi = wv + m * DIM + ti * 128;
    const float* wj = wv + m * DIM + tj * 128;
    const int tid = threadIdx.x;
    const int r = tid >> 1, c0 = (tid & 1) * 64;
    float inner = 0.f;
    const float4* g4 = (const float4*)&G[r * 128 + c0];
    const float4* w4 = (const float4*)&wj[c0];
#pragma unroll
    for (int t = 0; t < 16; ++t) {
        float4 g = g4[t], ww = w4[t];
        inner += g.x * ww.x + g.y * ww.y + g.z * ww.z + g.w * ww.w;
    }
    float s = wi[r] * inner;
    for (int off = 32; off; off >>= 1) s += __shfl_down(s, off);
    __shared__ float part[4];
    int lane = tid & 63, wx = tid >> 6;
    if (lane == 0) part[wx] = s;
    __syncthreads();
    if (tid == 0) {
        float tot = part[0] + part[1] + part[2] + part[3];
        if (ti != tj) tot *= 2.f;
        atomicAdd(&num[m], tot);
    }
}

// out = num0/|w0|^2 + 0.5*(num1/|w1|^2 + num2/|w2|^2)
__global__ __launch_bounds__(256)
void final_k(const float* __restrict__ num, const float* __restrict__ w,
             float* __restrict__ out) {
    __shared__ float red[256];
    int tid = threadIdx.x;
    float lam[3];
    for (int m = 0; m < 3; ++m) {
        float s = 0.f;
        for (int i = tid; i < DIM; i += 256) { float x = w[m * DIM + i]; s += x * x; }
        red[tid] = s; __syncthreads();
        for (int off = 128; off; off >>= 1) {
            if (tid < off) red[tid] += red[tid + off];
            __syncthreads();
        }
        lam[m] = num[m] / red[0]; __syncthreads();
    }
    if (tid == 0) out[0] = lam[0] + 0.5f * (lam[1] + lam[2]);
}

extern "C" void kernel_launch(void* const* d_in, const int* in_sizes, int n_in,
                              void* d_out, int out_size, void* d_ws, size_t ws_size,
                              hipStream_t stream) {
    const float* f0 = (const float*)d_in[0];
    const float* f1 = (const float*)d_in[1];
    const float* f2 = (const float*)d_in[2];

    char* base = (char*)d_ws;
    unsigned short* ft = (unsigned short*)base;                   // 48 MB bf16 f^T x3
    unsigned short* Q  = (unsigned short*)base;                   // overlays ft (dead after syrk)
    unsigned short* P  = (unsigned short*)(base + 50331648);      // 6 MB bf16 M x3
    float* G32 = (float*)(base + 56623104);                       // 7.08 MB packed-upper fp32 (LIVE)
    float* trbuf = (float*)(base + 63700992);                     // 64 floats (zeroed)
    float* num = trbuf + 40;                                      // 3 floats (zeroed region)
    float* v = (float*)(base + 63701248);                         // 3*1024
    float* w = v + 3 * DIM;                                       // 3*1024

    // zero G32 (7077888 B) + trbuf/num (256 B) in one async memset
    hipMemsetAsync(G32, 0, 7078144, stream);

    dim3 gt(DIM / 64, NROW / 64, 3);
    tconv_k<<<gt, 256, 0, stream>>>(f0, f1, f2, ft);

    // G = ft ft' (K=8192), split-K x4, XCD-combo swizzled flat grid (432)
    syrk_sk<<<432, 256, 0, stream>>>(ft, G32);
    // packed fp32 -> full bf16 P + trace (G32 preserved)
    convert_k<<<dim3(36, 1, 3), 256, 0, stream>>>(G32, trbuf, P);

    unsigned short* cur = P;
    unsigned short* nxt = Q;   // Q lives in the dead ft region
    for (int s = 0; s < NS; ++s) {
        sq_k<<<dim3(136, 1, 3), 256, 0, stream>>>(cur, trbuf + s * 3,
                                                  trbuf + (s + 1) * 3, nxt);
        unsigned short* t2 = cur; cur = nxt; nxt = t2;
    }
    // NS=5 (odd) => cur == Q

    dim3 b(256, 1, 1);
    dim3 gm(DIM / 4, 3, 1);
    mv_bf16<<<gm, b, 0, stream>>>(cur, nullptr, v);   // v = M*1
    mv_bf16<<<gm, b, 0, stream>>>(cur, v, w);         // w = M*v (polish)

    // num[m] = w' G32 w  (fp32 Gram, packed upper)
    ray_k<<<dim3(36, 3, 1), 256, 0, stream>>>(G32, w, num);
    final_k<<<1, 256, 0, stream>>>(num, w, (float*)d_out);
}